// Round 1
// baseline (1015.120 us; speedup 1.0000x reference)
//
#include <hip/hip_runtime.h>
#include <math.h>

#define N_SAMP 32768
#define K_COMP 2048
#define ZD 64
// 64 * (0.5*log(2*pi) + 0.5*log(64))
#define LNC 191.896324792608546f

#define WAVES 8
#define BLK (WAVES * 64)
#define KPW (K_COMP / WAVES)  // 256 components per wave

// ---------------------------------------------------------------------------
// prep: cker[k] = logits[k] - ||locs_k||^2 / 128 ; lse_out = logsumexp(logits)
// ---------------------------------------------------------------------------
__global__ __launch_bounds__(256) void prep_kernel(const float* __restrict__ locs,
                                                   const float* __restrict__ logits,
                                                   float* __restrict__ cker,
                                                   float* __restrict__ lse_out) {
    int k = blockIdx.x * 256 + threadIdx.x;
    const float* L = locs + (size_t)k * ZD;
    float s = 0.f;
#pragma unroll
    for (int d = 0; d < ZD; d += 4) {
        float4 v = *(const float4*)(L + d);
        s += v.x * v.x + v.y * v.y + v.z * v.z + v.w * v.w;
    }
    cker[k] = logits[k] - s * (1.0f / 128.0f);

    if (blockIdx.x == 0) {
        __shared__ float red[256];
        int tid = threadIdx.x;
        float lm = -INFINITY;
        for (int i = tid; i < K_COMP; i += 256) lm = fmaxf(lm, logits[i]);
        red[tid] = lm;
        __syncthreads();
        for (int off = 128; off > 0; off >>= 1) {
            if (tid < off) red[tid] = fmaxf(red[tid], red[tid + off]);
            __syncthreads();
        }
        float M = red[0];
        __syncthreads();
        float ls = 0.f;
        for (int i = tid; i < K_COMP; i += 256) ls += __expf(logits[i] - M);
        red[tid] = ls;
        __syncthreads();
        for (int off = 128; off > 0; off >>= 1) {
            if (tid < off) red[tid] += red[tid + off];
            __syncthreads();
        }
        if (tid == 0) *lse_out = M + __logf(red[0]);
    }
}

// ---------------------------------------------------------------------------
// main: lane <-> sample, wave <-> K-chunk (k wave-uniform -> s_load for locs)
// ---------------------------------------------------------------------------
__global__ __launch_bounds__(BLK, 4) void mix_kernel(
    const float* __restrict__ x, const float* __restrict__ locs,
    const float* __restrict__ cker, const float* __restrict__ lse_ptr,
    float* __restrict__ out) {
    __shared__ float xs[64][68];  // +4 pad keeps float4 alignment, breaks pow2 stride
    __shared__ float rm[WAVES][64];
    __shared__ float rs[WAVES][64];
    __shared__ int   rai[WAVES][64];
    __shared__ int   amax_sh[64];

    const int tid = threadIdx.x;
    const int lane = tid & 63;
    const int wave = __builtin_amdgcn_readfirstlane(tid >> 6);
    const int samp_base = blockIdx.x * 64;

    // stage x tile [64 samples x 64 dims] into LDS, coalesced
    {
        const float4* xg = (const float4*)(x + (size_t)samp_base * ZD);
#pragma unroll
        for (int i = tid; i < 64 * 16; i += BLK) {
            int row = i >> 4, c4 = i & 15;
            *(float4*)&xs[row][c4 * 4] = xg[i];
        }
    }
    __syncthreads();

    // this thread's sample row -> registers
    float xr[ZD];
#pragma unroll
    for (int d = 0; d < ZD; d += 4) {
        float4 v = *(const float4*)&xs[lane][d];
        xr[d] = v.x; xr[d + 1] = v.y; xr[d + 2] = v.z; xr[d + 3] = v.w;
    }
    float xsq = 0.f;
#pragma unroll
    for (int d = 0; d < ZD; ++d) xsq = fmaf(xr[d], xr[d], xsq);
    const float bias = -xsq * (1.0f / 128.0f) - LNC;

    // online logsumexp + first-tie argmax over this wave's K-chunk
    float m = -INFINITY, sum = 0.f;
    int ai = 0;
    const int kbase = wave * KPW;
    for (int k0 = kbase; k0 < kbase + KPW; k0 += 4) {
        const float* __restrict__ L0 = locs + (size_t)(k0 + 0) * ZD;
        const float* __restrict__ L1 = locs + (size_t)(k0 + 1) * ZD;
        const float* __restrict__ L2 = locs + (size_t)(k0 + 2) * ZD;
        const float* __restrict__ L3 = locs + (size_t)(k0 + 3) * ZD;
        float a0 = 0.f, a1 = 0.f, a2 = 0.f, a3 = 0.f;
#pragma unroll
        for (int d = 0; d < ZD; ++d) {
            float xd = xr[d];
            a0 = fmaf(xd, L0[d], a0);
            a1 = fmaf(xd, L1[d], a1);
            a2 = fmaf(xd, L2[d], a2);
            a3 = fmaf(xd, L3[d], a3);
        }
        float w0 = fmaf(a0, 1.0f / 64.0f, cker[k0 + 0] + bias);
        float w1 = fmaf(a1, 1.0f / 64.0f, cker[k0 + 1] + bias);
        float w2 = fmaf(a2, 1.0f / 64.0f, cker[k0 + 2] + bias);
        float w3 = fmaf(a3, 1.0f / 64.0f, cker[k0 + 3] + bias);
        float wmax = fmaxf(fmaxf(w0, w1), fmaxf(w2, w3));
        float nm = fmaxf(m, wmax);
        float e = __expf(w0 - nm) + __expf(w1 - nm) + __expf(w2 - nm) + __expf(w3 - nm);
        sum = fmaf(sum, __expf(m - nm), e);
        // first-max argmax (strict >, ascending k)
        float t = m;
        ai = (w0 > t) ? (k0 + 0) : ai; t = fmaxf(t, w0);
        ai = (w1 > t) ? (k0 + 1) : ai; t = fmaxf(t, w1);
        ai = (w2 > t) ? (k0 + 2) : ai; t = fmaxf(t, w2);
        ai = (w3 > t) ? (k0 + 3) : ai;
        m = nm;
    }

    rm[wave][lane] = m;
    rs[wave][lane] = sum;
    rai[wave][lane] = ai;
    __syncthreads();

    if (wave == 0) {
        float M = -INFINITY, S = 0.f;
        int A = 0;
#pragma unroll
        for (int w = 0; w < WAVES; ++w) {
            float mw = rm[w][lane], sw = rs[w][lane];
            float nM = fmaxf(M, mw);
            S = S * __expf(M - nM) + sw * __expf(mw - nM);
            A = (mw > M) ? rai[w][lane] : A;  // wave order ascending => first tie kept
            M = nM;
        }
        out[samp_base + lane] = M + __logf(S) - lse_ptr[0];
        amax_sh[lane] = A;
    }
    __syncthreads();

    // cooperative coalesced write of quantized = locs[argmax]
    float* oq = out + N_SAMP + (size_t)samp_base * ZD;
    for (int i = tid; i < 64 * ZD; i += BLK) {
        int srow = i >> 6, d = i & 63;
        oq[i] = locs[(size_t)amax_sh[srow] * ZD + d];
    }
}

extern "C" void kernel_launch(void* const* d_in, const int* in_sizes, int n_in,
                              void* d_out, int out_size, void* d_ws, size_t ws_size,
                              hipStream_t stream) {
    const float* x      = (const float*)d_in[0];
    const float* locs   = (const float*)d_in[1];
    const float* logits = (const float*)d_in[2];
    float* out  = (float*)d_out;
    float* cker = (float*)d_ws;          // K_COMP floats
    float* lse  = cker + K_COMP;         // 1 float

    prep_kernel<<<K_COMP / 256, 256, 0, stream>>>(locs, logits, cker, lse);
    mix_kernel<<<N_SAMP / 64, BLK, 0, stream>>>(x, locs, cker, lse, out);
}

// Round 2
// 196.342 us; speedup vs baseline: 5.1702x; 5.1702x over previous
//
#include <hip/hip_runtime.h>
#include <math.h>

#define N_SAMP 32768
#define K_COMP 2048
#define ZD 64
// 64 * (0.5*log(2*pi) + 0.5*log(64))
#define LNC 191.896324792608546f

typedef __attribute__((ext_vector_type(8))) short short8;
typedef __attribute__((ext_vector_type(4))) float v4f;

__device__ inline unsigned short f2bf(float f) {
    unsigned int u = __float_as_uint(f);
    u += 0x7fffu + ((u >> 16) & 1u);  // RNE
    return (unsigned short)(u >> 16);
}
__device__ inline float bf2f(unsigned short h) {
    return __uint_as_float(((unsigned int)h) << 16);
}

// ---------------------------------------------------------------------------
// prep: ck[k] = logits[k] - ||locs_k||^2/128 (exact fp32);
//       locs -> bf16 hi/lo split arrays; lse = logsumexp(logits) exact.
// ---------------------------------------------------------------------------
__global__ __launch_bounds__(256) void prep_kernel(
    const float* __restrict__ locs, const float* __restrict__ logits,
    float* __restrict__ ck, float* __restrict__ lse_out,
    unsigned short* __restrict__ lhi, unsigned short* __restrict__ llo) {
    int k = blockIdx.x * 256 + threadIdx.x;
    const float* L = locs + (size_t)k * ZD;
    float s = 0.f;
#pragma unroll
    for (int d = 0; d < ZD; d += 4) {
        float4 v = *(const float4*)(L + d);
        s += v.x * v.x + v.y * v.y + v.z * v.z + v.w * v.w;
        ushort4 hh, ll;
        hh.x = f2bf(v.x); ll.x = f2bf(v.x - bf2f(hh.x));
        hh.y = f2bf(v.y); ll.y = f2bf(v.y - bf2f(hh.y));
        hh.z = f2bf(v.z); ll.z = f2bf(v.z - bf2f(hh.z));
        hh.w = f2bf(v.w); ll.w = f2bf(v.w - bf2f(hh.w));
        *(ushort4*)(lhi + (size_t)k * ZD + d) = hh;
        *(ushort4*)(llo + (size_t)k * ZD + d) = ll;
    }
    ck[k] = logits[k] - s * (1.0f / 128.0f);

    if (blockIdx.x == 0) {
        __shared__ float red[256];
        int tid = threadIdx.x;
        float lm = -INFINITY;
        for (int i = tid; i < K_COMP; i += 256) lm = fmaxf(lm, logits[i]);
        red[tid] = lm;
        __syncthreads();
        for (int off = 128; off > 0; off >>= 1) {
            if (tid < off) red[tid] = fmaxf(red[tid], red[tid + off]);
            __syncthreads();
        }
        float M = red[0];
        __syncthreads();
        float ls = 0.f;
        for (int i = tid; i < K_COMP; i += 256) ls += __expf(logits[i] - M);
        red[tid] = ls;
        __syncthreads();
        for (int off = 128; off > 0; off >>= 1) {
            if (tid < off) red[tid] += red[tid + off];
            __syncthreads();
        }
        if (tid == 0) *lse_out = M + __logf(red[0]);
    }
}

// ---------------------------------------------------------------------------
// main: MFMA split-bf16 GEMM + fused online logsumexp/argmax.
// Block: 512 thr = 8 waves = 4 sample-groups(16) x 2 k-groups.
// Wave tile per iter: C[16 comps][16 samps] via 6x mfma_f32_16x16x32_bf16.
// ---------------------------------------------------------------------------
__global__ __launch_bounds__(512, 4) void mix_kernel(
    const float* __restrict__ x, const float* __restrict__ locs,
    const unsigned short* __restrict__ lhi, const unsigned short* __restrict__ llo,
    const float* __restrict__ ck, const float* __restrict__ lse_ptr,
    float* __restrict__ out) {

    __shared__ float sm[2][4][16];
    __shared__ float ss[2][4][16];
    __shared__ int   sa[2][4][16];
    __shared__ int   amax_sh[64];

    const int tid  = threadIdx.x;
    const int lane = tid & 63;
    const int wave = tid >> 6;       // 0..7
    const int sg   = wave & 3;       // sample group
    const int kg   = wave >> 2;      // k group (0,1)
    const int n    = lane & 15;      // sample col within group / comp row within tile
    const int quad = lane >> 4;      // 0..3
    const int sbase = blockIdx.x * 64;
    const int srow  = sbase + sg * 16 + n;

    // ---- B fragments (x), converted fp32 -> bf16 hi/lo on the fly; xsq partial.
    // B layout (16x16x32): lane holds B[kdim=quad*8+j][n=lane&15] = x[srow][d=dc*32+quad*8+j]
    short8 bh0, bh1, bl0, bl1;
    float xsp = 0.f;
    {
        const float* xp = x + (size_t)srow * ZD + quad * 8;
        float4 v0 = *(const float4*)xp;
        float4 v1 = *(const float4*)(xp + 4);
        float4 v2 = *(const float4*)(xp + 32);
        float4 v3 = *(const float4*)(xp + 36);
        float a[8] = {v0.x, v0.y, v0.z, v0.w, v1.x, v1.y, v1.z, v1.w};
        float b[8] = {v2.x, v2.y, v2.z, v2.w, v3.x, v3.y, v3.z, v3.w};
#pragma unroll
        for (int j = 0; j < 8; ++j) {
            unsigned short h0 = f2bf(a[j]);
            bh0[j] = (short)h0;
            bl0[j] = (short)f2bf(a[j] - bf2f(h0));
            unsigned short h1 = f2bf(b[j]);
            bh1[j] = (short)h1;
            bl1[j] = (short)f2bf(b[j] - bf2f(h1));
            xsp = fmaf(a[j], a[j], xsp);
            xsp = fmaf(b[j], b[j], xsp);
        }
    }
    // full ||x||^2 for sample srow: sum partials across the 4 quads
    float xs = xsp + __shfl_xor(xsp, 16);
    xs += __shfl_xor(xs, 32);
    const float bias = -xs * (1.0f / 128.0f) - LNC;

    // ---- A fragment stream (locs hi/lo), double-buffered in registers.
    // A layout: lane holds A[m=lane&15][kdim=quad*8+j] = locs[ktile+n][d]
    const unsigned short* ph = lhi + (size_t)(kg * 16 + n) * ZD + quad * 8;
    const unsigned short* pl = llo + (size_t)(kg * 16 + n) * ZD + quad * 8;
    const float* pc = ck + kg * 16 + quad * 4;

    short8 ah0 = *(const short8*)ph;
    short8 ah1 = *(const short8*)(ph + 32);
    short8 al0 = *(const short8*)pl;
    short8 al1 = *(const short8*)(pl + 32);
    float4 c4  = *(const float4*)pc;

    float m = -1e30f, sum = 0.f;
    int ai = 0;

    for (int it = 0; it < 64; ++it) {
        const int itn = (it < 63) ? (it + 1) : 63;  // last prefetch clamped (unused)
        const unsigned short* phn = ph + (size_t)itn * (32 * ZD);
        const unsigned short* pln = pl + (size_t)itn * (32 * ZD);
        short8 nh0 = *(const short8*)phn;
        short8 nh1 = *(const short8*)(phn + 32);
        short8 nl0 = *(const short8*)pln;
        short8 nl1 = *(const short8*)(pln + 32);
        float4 nc4 = *(const float4*)(pc + itn * 32);

        v4f a0 = {0.f, 0.f, 0.f, 0.f};
        v4f a1 = {0.f, 0.f, 0.f, 0.f};
        // dot = hi*hi + hi*lo + lo*hi  (lo*lo dropped, ~2^-18 relative)
        a0 = __builtin_amdgcn_mfma_f32_16x16x32_bf16(ah0, bh0, a0, 0, 0, 0);
        a1 = __builtin_amdgcn_mfma_f32_16x16x32_bf16(ah1, bh1, a1, 0, 0, 0);
        a0 = __builtin_amdgcn_mfma_f32_16x16x32_bf16(ah0, bl0, a0, 0, 0, 0);
        a1 = __builtin_amdgcn_mfma_f32_16x16x32_bf16(ah1, bl1, a1, 0, 0, 0);
        a0 = __builtin_amdgcn_mfma_f32_16x16x32_bf16(al0, bh0, a0, 0, 0, 0);
        a1 = __builtin_amdgcn_mfma_f32_16x16x32_bf16(al1, bh1, a1, 0, 0, 0);

        // wlp for this lane's 4 comps (C row = quad*4 + reg, col = n)
        float w0 = fmaf(a0.x + a1.x, 1.0f / 64.f, c4.x + bias);
        float w1 = fmaf(a0.y + a1.y, 1.0f / 64.f, c4.y + bias);
        float w2 = fmaf(a0.z + a1.z, 1.0f / 64.f, c4.z + bias);
        float w3 = fmaf(a0.w + a1.w, 1.0f / 64.f, c4.w + bias);

        float wm = fmaxf(fmaxf(w0, w1), fmaxf(w2, w3));
        float nm = fmaxf(m, wm);
        float e = __expf(w0 - nm) + __expf(w1 - nm) + __expf(w2 - nm) + __expf(w3 - nm);
        sum = fmaf(sum, __expf(m - nm), e);

        const int kq = it * 32 + kg * 16 + quad * 4;
        float t = m;
        ai = (w0 > t) ? (kq + 0) : ai; t = fmaxf(t, w0);
        ai = (w1 > t) ? (kq + 1) : ai; t = fmaxf(t, w1);
        ai = (w2 > t) ? (kq + 2) : ai; t = fmaxf(t, w2);
        ai = (w3 > t) ? (kq + 3) : ai;
        m = nm;

        ah0 = nh0; ah1 = nh1; al0 = nl0; al1 = nl1; c4 = nc4;
    }

    // ---- combine across quads (disjoint k-subsets, same sample col n)
#pragma unroll
    for (int d = 16; d <= 32; d <<= 1) {
        float om = __shfl_xor(m, d);
        float os = __shfl_xor(sum, d);
        int   oa = __shfl_xor(ai, d);
        float nm = fmaxf(m, om);
        sum = sum * __expf(m - nm) + os * __expf(om - nm);
        ai = (om > m || (om == m && oa < ai)) ? oa : ai;  // exact-tie: smaller k
        m = nm;
    }

    if (lane < 16) {
        sm[kg][sg][lane] = m;
        ss[kg][sg][lane] = sum;
        sa[kg][sg][lane] = ai;
    }
    __syncthreads();

    // ---- combine the two k-groups, write log_prob, stash argmax
    if (kg == 0 && lane < 16) {
        float m1 = sm[1][sg][lane], s1 = ss[1][sg][lane];
        int   a1i = sa[1][sg][lane];
        float nm = fmaxf(m, m1);
        float S = sum * __expf(m - nm) + s1 * __expf(m1 - nm);
        int A = (m1 > m || (m1 == m && a1i < ai)) ? a1i : ai;
        out[srow] = nm + __logf(S) - lse_ptr[0];
        amax_sh[sg * 16 + lane] = A;
    }
    __syncthreads();

    // ---- quantized = locs[argmax], cooperative coalesced float4 writes
    const float4* lq = (const float4*)locs;
    float4* oq = (float4*)(out + N_SAMP + (size_t)sbase * ZD);
#pragma unroll
    for (int i = tid; i < 64 * (ZD / 4); i += 512) {
        int r = i >> 4, c = i & 15;
        oq[i] = lq[(size_t)amax_sh[r] * (ZD / 4) + c];
    }
}

extern "C" void kernel_launch(void* const* d_in, const int* in_sizes, int n_in,
                              void* d_out, int out_size, void* d_ws, size_t ws_size,
                              hipStream_t stream) {
    const float* x      = (const float*)d_in[0];
    const float* locs   = (const float*)d_in[1];
    const float* logits = (const float*)d_in[2];
    float* out = (float*)d_out;

    float* ck  = (float*)d_ws;                       // 2048 f
    float* lse = ck + K_COMP;                        // 1 f
    unsigned short* lhi = (unsigned short*)(ck + K_COMP + 4);      // 16B-aligned
    unsigned short* llo = lhi + (size_t)K_COMP * ZD;

    prep_kernel<<<K_COMP / 256, 256, 0, stream>>>(locs, logits, ck, lse, lhi, llo);
    mix_kernel<<<N_SAMP / 64, 512, 0, stream>>>(x, locs, lhi, llo, ck, lse, out);
}

// Round 3
// 103.775 us; speedup vs baseline: 9.7819x; 1.8920x over previous
//
#include <hip/hip_runtime.h>
#include <math.h>

#define N_SAMP 32768
#define K_COMP 2048
#define ZD 64
#define LNC 191.896324792608546f   // 64*(0.5*log(2pi) + 0.5*log(64))
#define LN2F 0.69314718055994531f
#define INV_LN2 1.44269504088896340f
// wlp = dot/64 + ck + bias ; base-2: v2 = dot*(1/(64 ln2)) + ck2
#define S2C 0.02254211001388974f   // 1/(64*ln2)

#define TILES_TOT 128              // K_COMP/16
#define KG 4
#define TILES (TILES_TOT / KG)     // 32 tiles per wave

typedef __attribute__((ext_vector_type(8))) short short8;
typedef __attribute__((ext_vector_type(4))) float v4f;

#if __has_builtin(__builtin_amdgcn_exp2f)
#define EXP2(x) __builtin_amdgcn_exp2f(x)
#else
#define EXP2(x) exp2f(x)
#endif

__device__ inline unsigned short f2bf(float f) {
    unsigned int u = __float_as_uint(f);
    u += 0x7fffu + ((u >> 16) & 1u);  // RNE
    return (unsigned short)(u >> 16);
}
__device__ inline float bf2f(unsigned short h) {
    return __uint_as_float(((unsigned int)h) << 16);
}

// ---------------------------------------------------------------------------
// prep: build fragment-linearized locs hi/lo (lf), ck2, lse.
// lf layout: tile T (16 comps) -> 4 KB block: region r in {hi_d0_31, hi_d32_63,
// lo_d0_31, lo_d32_63} x lane l in [0,64): 16B chunk = split(locs[T*16+(l&15)]
// [ (r&1)*32 + (l>>4)*8 .. +8 ]).  Mix reads it with lane-contiguous dwordx4.
// Thread (T,l): 4 coalesced-ish float4 reads, 4 coalesced 16B stores.
// ---------------------------------------------------------------------------
__global__ __launch_bounds__(256) void prep_kernel(
    const float* __restrict__ locs, const float* __restrict__ logits,
    float* __restrict__ ck2, float* __restrict__ lse_out,
    char* __restrict__ lf) {
    int gid = blockIdx.x * 256 + threadIdx.x;   // 0..8191
    int T = gid >> 6;
    int l = gid & 63;
    int n = l & 15, q = l >> 4;
    int k = T * 16 + n;

    const float* src = locs + (size_t)k * ZD + q * 8;
    float4 u0 = *(const float4*)(src);
    float4 u1 = *(const float4*)(src + 4);
    float4 u2 = *(const float4*)(src + 32);
    float4 u3 = *(const float4*)(src + 36);
    float a[8] = {u0.x, u0.y, u0.z, u0.w, u1.x, u1.y, u1.z, u1.w};
    float b[8] = {u2.x, u2.y, u2.z, u2.w, u3.x, u3.y, u3.z, u3.w};

    short8 h0, h1, l0, l1;
    float sq = 0.f;
#pragma unroll
    for (int j = 0; j < 8; ++j) {
        unsigned short ha = f2bf(a[j]);
        h0[j] = (short)ha; l0[j] = (short)f2bf(a[j] - bf2f(ha));
        unsigned short hb = f2bf(b[j]);
        h1[j] = (short)hb; l1[j] = (short)f2bf(b[j] - bf2f(hb));
        sq = fmaf(a[j], a[j], sq);
        sq = fmaf(b[j], b[j], sq);
    }
    char* dst = lf + (size_t)T * 4096 + l * 16;
    *(short8*)(dst)        = h0;
    *(short8*)(dst + 1024) = h1;
    *(short8*)(dst + 2048) = l0;
    *(short8*)(dst + 3072) = l1;

    // row ||locs_k||^2: quads of the same n sit at lanes n, n+16, n+32, n+48
    sq += __shfl_xor(sq, 16);
    sq += __shfl_xor(sq, 32);
    if (q == 0) ck2[k] = (logits[k] - sq * (1.0f / 128.0f)) * INV_LN2;

    if (blockIdx.x == 0) {
        __shared__ float red[256];
        int tid = threadIdx.x;
        float lm = -INFINITY;
        for (int i = tid; i < K_COMP; i += 256) lm = fmaxf(lm, logits[i]);
        red[tid] = lm;
        __syncthreads();
        for (int off = 128; off > 0; off >>= 1) {
            if (tid < off) red[tid] = fmaxf(red[tid], red[tid + off]);
            __syncthreads();
        }
        float M = red[0];
        __syncthreads();
        float ls = 0.f;
        for (int i = tid; i < K_COMP; i += 256) ls += __expf(logits[i] - M);
        red[tid] = ls;
        __syncthreads();
        for (int off = 128; off > 0; off >>= 1) {
            if (tid < off) red[tid] += red[tid + off];
            __syncthreads();
        }
        if (tid == 0) *lse_out = M + __logf(red[0]);
    }
}

// ---------------------------------------------------------------------------
// mix: block = 512 thr = 8 waves = 2 sample-groups(32 samp) x 4 k-groups.
// Wave: B-frags for 32 samples loop-invariant in regs; per iter one 16-comp
// tile: 4 coalesced b128 A-loads (ring-2 prefetch) + 12 chained MFMA +
// base-2 online logsumexp/argmax epilogue.
// ---------------------------------------------------------------------------
__global__ __launch_bounds__(512, 4) void mix_kernel(
    const float* __restrict__ x, const float* __restrict__ locs,
    const char* __restrict__ lf, const float* __restrict__ ck2,
    const float* __restrict__ lse_ptr, float* __restrict__ out) {

    __shared__ float sm[KG][2][32];
    __shared__ float ss[KG][2][32];
    __shared__ int   sa[KG][2][32];
    __shared__ float xsq_sh[64];
    __shared__ int   amax_sh[64];

    const int tid  = threadIdx.x;
    const int lane = tid & 63;
    const int wave = tid >> 6;                                   // 0..7
    const int kg   = __builtin_amdgcn_readfirstlane(wave & 3);   // 0..3
    const int sgp  = __builtin_amdgcn_readfirstlane(wave >> 2);  // 0..1
    const int n    = lane & 15;
    const int quad = lane >> 4;
    const int sA   = blockIdx.x * 64 + sgp * 32 + n;
    const int sB   = sA + 16;

    // ---- B fragments (x) for 2 sample tiles, fp32 -> bf16 hi/lo; xsq partials
    short8 bhA0, bhA1, blA0, blA1, bhB0, bhB1, blB0, blB1;
    float xsA, xsB;
    {
        const float* xp = x + (size_t)sA * ZD + quad * 8;
        float4 u0 = *(const float4*)(xp);
        float4 u1 = *(const float4*)(xp + 4);
        float4 u2 = *(const float4*)(xp + 32);
        float4 u3 = *(const float4*)(xp + 36);
        const float* yp = x + (size_t)sB * ZD + quad * 8;
        float4 v0 = *(const float4*)(yp);
        float4 v1 = *(const float4*)(yp + 4);
        float4 v2 = *(const float4*)(yp + 32);
        float4 v3 = *(const float4*)(yp + 36);
        float a[8] = {u0.x, u0.y, u0.z, u0.w, u1.x, u1.y, u1.z, u1.w};
        float b[8] = {u2.x, u2.y, u2.z, u2.w, u3.x, u3.y, u3.z, u3.w};
        float c[8] = {v0.x, v0.y, v0.z, v0.w, v1.x, v1.y, v1.z, v1.w};
        float d[8] = {v2.x, v2.y, v2.z, v2.w, v3.x, v3.y, v3.z, v3.w};
        float pa = 0.f, pb = 0.f;
#pragma unroll
        for (int j = 0; j < 8; ++j) {
            unsigned short h;
            h = f2bf(a[j]); bhA0[j] = (short)h; blA0[j] = (short)f2bf(a[j] - bf2f(h));
            h = f2bf(b[j]); bhA1[j] = (short)h; blA1[j] = (short)f2bf(b[j] - bf2f(h));
            h = f2bf(c[j]); bhB0[j] = (short)h; blB0[j] = (short)f2bf(c[j] - bf2f(h));
            h = f2bf(d[j]); bhB1[j] = (short)h; blB1[j] = (short)f2bf(d[j] - bf2f(h));
            pa = fmaf(a[j], a[j], pa); pa = fmaf(b[j], b[j], pa);
            pb = fmaf(c[j], c[j], pb); pb = fmaf(d[j], d[j], pb);
        }
        pa += __shfl_xor(pa, 16); pa += __shfl_xor(pa, 32);
        pb += __shfl_xor(pb, 16); pb += __shfl_xor(pb, 32);
        xsA = pa; xsB = pb;
    }
    if (kg == 0) {
        if (quad == 0) xsq_sh[sgp * 32 + n] = xsA;
        if (quad == 1) xsq_sh[sgp * 32 + 16 + n] = xsB;
    }

    // ---- A-frag stream, ring-2 prefetch, coalesced (lane*16 contiguous)
    const char* aw = lf + (size_t)kg * TILES * 4096 + lane * 16;
    const float* ckw = ck2 + kg * TILES * 16 + quad * 4;
    const int kb0 = kg * TILES * 16 + quad * 4;

    short8 fa[2][4];
    float4 fc[2];

#define LOADA(slot, tt) do {                                     \
    const char* _p = aw + (size_t)(tt) * 4096;                   \
    fa[slot][0] = *(const short8*)(_p);                          \
    fa[slot][1] = *(const short8*)(_p + 1024);                   \
    fa[slot][2] = *(const short8*)(_p + 2048);                   \
    fa[slot][3] = *(const short8*)(_p + 3072);                   \
    fc[slot] = *(const float4*)(ckw + (tt) * 16);                \
} while (0)

    float mA = -1e30f, sumA = 0.f; int aiA = 0;
    float mB = -1e30f, sumB = 0.f; int aiB = 0;

#define COMPUTE(slot, tt) do {                                                 \
    v4f accA = {0.f, 0.f, 0.f, 0.f};                                           \
    v4f accB = {0.f, 0.f, 0.f, 0.f};                                           \
    accA = __builtin_amdgcn_mfma_f32_16x16x32_bf16(fa[slot][0], bhA0, accA, 0, 0, 0); \
    accB = __builtin_amdgcn_mfma_f32_16x16x32_bf16(fa[slot][0], bhB0, accB, 0, 0, 0); \
    accA = __builtin_amdgcn_mfma_f32_16x16x32_bf16(fa[slot][1], bhA1, accA, 0, 0, 0); \
    accB = __builtin_amdgcn_mfma_f32_16x16x32_bf16(fa[slot][1], bhB1, accB, 0, 0, 0); \
    accA = __builtin_amdgcn_mfma_f32_16x16x32_bf16(fa[slot][0], blA0, accA, 0, 0, 0); \
    accB = __builtin_amdgcn_mfma_f32_16x16x32_bf16(fa[slot][0], blB0, accB, 0, 0, 0); \
    accA = __builtin_amdgcn_mfma_f32_16x16x32_bf16(fa[slot][1], blA1, accA, 0, 0, 0); \
    accB = __builtin_amdgcn_mfma_f32_16x16x32_bf16(fa[slot][1], blB1, accB, 0, 0, 0); \
    accA = __builtin_amdgcn_mfma_f32_16x16x32_bf16(fa[slot][2], bhA0, accA, 0, 0, 0); \
    accB = __builtin_amdgcn_mfma_f32_16x16x32_bf16(fa[slot][2], bhB0, accB, 0, 0, 0); \
    accA = __builtin_amdgcn_mfma_f32_16x16x32_bf16(fa[slot][3], bhA1, accA, 0, 0, 0); \
    accB = __builtin_amdgcn_mfma_f32_16x16x32_bf16(fa[slot][3], bhB1, accB, 0, 0, 0); \
    const int kb = kb0 + (tt) * 16;                                            \
    float4 cc = fc[slot];                                                      \
    {                                                                          \
        float w0 = fmaf(accA.x, S2C, cc.x);                                    \
        float w1 = fmaf(accA.y, S2C, cc.y);                                    \
        float w2 = fmaf(accA.z, S2C, cc.z);                                    \
        float w3 = fmaf(accA.w, S2C, cc.w);                                    \
        float t = mA;                                                          \
        aiA = (w0 > t) ? (kb + 0) : aiA; t = fmaxf(t, w0);                     \
        aiA = (w1 > t) ? (kb + 1) : aiA; t = fmaxf(t, w1);                     \
        aiA = (w2 > t) ? (kb + 2) : aiA; t = fmaxf(t, w2);                     \
        aiA = (w3 > t) ? (kb + 3) : aiA; t = fmaxf(t, w3);                     \
        float e = EXP2(w0 - t) + EXP2(w1 - t) + EXP2(w2 - t) + EXP2(w3 - t);   \
        sumA = fmaf(sumA, EXP2(mA - t), e);                                    \
        mA = t;                                                                \
    }                                                                          \
    {                                                                          \
        float w0 = fmaf(accB.x, S2C, cc.x);                                    \
        float w1 = fmaf(accB.y, S2C, cc.y);                                    \
        float w2 = fmaf(accB.z, S2C, cc.z);                                    \
        float w3 = fmaf(accB.w, S2C, cc.w);                                    \
        float t = mB;                                                          \
        aiB = (w0 > t) ? (kb + 0) : aiB; t = fmaxf(t, w0);                     \
        aiB = (w1 > t) ? (kb + 1) : aiB; t = fmaxf(t, w1);                     \
        aiB = (w2 > t) ? (kb + 2) : aiB; t = fmaxf(t, w2);                     \
        aiB = (w3 > t) ? (kb + 3) : aiB; t = fmaxf(t, w3);                     \
        float e = EXP2(w0 - t) + EXP2(w1 - t) + EXP2(w2 - t) + EXP2(w3 - t);   \
        sumB = fmaf(sumB, EXP2(mB - t), e);                                    \
        mB = t;                                                                \
    }                                                                          \
} while (0)

    LOADA(0, 0);
    for (int t = 0; t < TILES; t += 2) {
        int t1 = (t + 1 < TILES) ? (t + 1) : (TILES - 1);
        LOADA(1, t1);
        COMPUTE(0, t);
        int t2 = (t + 2 < TILES) ? (t + 2) : (TILES - 1);
        LOADA(0, t2);
        COMPUTE(1, t + 1);
    }

    // ---- merge the 4 quads (disjoint comp subsets, same sample column)
#pragma unroll
    for (int d = 16; d <= 32; d <<= 1) {
        float om, os; int oa;
        om = __shfl_xor(mA, d); os = __shfl_xor(sumA, d); oa = __shfl_xor(aiA, d);
        {
            float nm = fmaxf(mA, om);
            sumA = sumA * EXP2(mA - nm) + os * EXP2(om - nm);
            aiA = (om > mA || (om == mA && oa < aiA)) ? oa : aiA;
            mA = nm;
        }
        om = __shfl_xor(mB, d); os = __shfl_xor(sumB, d); oa = __shfl_xor(aiB, d);
        {
            float nm = fmaxf(mB, om);
            sumB = sumB * EXP2(mB - nm) + os * EXP2(om - nm);
            aiB = (om > mB || (om == mB && oa < aiB)) ? oa : aiB;
            mB = nm;
        }
    }
    if (quad == 0) { sm[kg][sgp][n] = mA; ss[kg][sgp][n] = sumA; sa[kg][sgp][n] = aiA; }
    if (quad == 1) { sm[kg][sgp][16 + n] = mB; ss[kg][sgp][16 + n] = sumB; sa[kg][sgp][16 + n] = aiB; }
    __syncthreads();

    // ---- merge KG k-groups, write log_prob, stash argmax
    if (tid < 64) {
        int g = tid >> 5, sl = tid & 31;
        float M = -1e30f, S = 0.f; int A = 0;
#pragma unroll
        for (int k = 0; k < KG; ++k) {
            float mw = sm[k][g][sl], sw = ss[k][g][sl];
            int aw2 = sa[k][g][sl];
            float nm = fmaxf(M, mw);
            S = S * EXP2(M - nm) + sw * EXP2(mw - nm);
            A = (mw > M || (mw == M && aw2 < A)) ? aw2 : A;  // ascending kg order
            M = nm;
        }
        float bias = -xsq_sh[tid] * (1.0f / 128.0f) - LNC;
        out[blockIdx.x * 64 + tid] = fmaf(M + __log2f(S), LN2F, bias - lse_ptr[0]);
        amax_sh[tid] = A;
    }
    __syncthreads();

    // ---- quantized = locs[argmax], cooperative coalesced float4 writes
    const float4* lq = (const float4*)locs;
    float4* oq = (float4*)(out + N_SAMP + (size_t)blockIdx.x * 64 * ZD);
#pragma unroll
    for (int i = tid; i < 64 * (ZD / 4); i += 512) {
        int r = i >> 4, c = i & 15;
        oq[i] = lq[(size_t)amax_sh[r] * (ZD / 4) + c];
    }
#undef LOADA
#undef COMPUTE
}

extern "C" void kernel_launch(void* const* d_in, const int* in_sizes, int n_in,
                              void* d_out, int out_size, void* d_ws, size_t ws_size,
                              hipStream_t stream) {
    const float* x      = (const float*)d_in[0];
    const float* locs   = (const float*)d_in[1];
    const float* logits = (const float*)d_in[2];
    float* out = (float*)d_out;

    float* ck2 = (float*)d_ws;                 // 2048 floats
    float* lse = ck2 + K_COMP;                 // 1 float
    char*  lf  = (char*)d_ws + 16384;          // 512 KB fragment-linearized locs

    prep_kernel<<<32, 256, 0, stream>>>(locs, logits, ck2, lse, lf);
    mix_kernel<<<N_SAMP / 64, 512, 0, stream>>>(x, locs, lf, ck2, lse, out);
}

// Round 4
// 97.143 us; speedup vs baseline: 10.4497x; 1.0683x over previous
//
#include <hip/hip_runtime.h>
#include <math.h>

#define N_SAMP 32768
#define K_COMP 2048
#define ZD 64
#define LNC 191.896324792608546f   // 64*(0.5*log(2pi) + 0.5*log(64))
#define LN2F 0.69314718055994531f
#define INV_LN2 1.44269504088896340f
// w = dot*(1/(64 ln2)) + ck2 ; wlp_nat = w*ln2 + bias_nat
#define S2C 0.02254211001388974f   // 1/(64*ln2)

#define TILES_TOT 128              // K_COMP/16
#define KG 4
#define TILES (TILES_TOT / KG)     // 32 tiles per wave

typedef __attribute__((ext_vector_type(8))) short short8;
typedef __attribute__((ext_vector_type(4))) float v4f;

#if __has_builtin(__builtin_amdgcn_exp2f)
#define EXP2(x) __builtin_amdgcn_exp2f(x)
#else
#define EXP2(x) exp2f(x)
#endif

__device__ inline unsigned short f2bf(float f) {
    unsigned int u = __float_as_uint(f);
    u += 0x7fffu + ((u >> 16) & 1u);  // RNE
    return (unsigned short)(u >> 16);
}
__device__ inline float bf2f(unsigned short h) {
    return __uint_as_float(((unsigned int)h) << 16);
}

// ---------------------------------------------------------------------------
// prep: blocks 0..31 build fragment-linearized locs hi/lo (lf) + ck2.
//       block 32 computes lse = logsumexp(logits) concurrently (wave shfl).
// lf layout: tile T (16 comps) -> 4 KB: 4 regions x 64 lanes x 16 B, exactly
// the mix kernel's A-fragment order (lane-contiguous dwordx4 loads).
// ---------------------------------------------------------------------------
__global__ __launch_bounds__(256) void prep_kernel(
    const float* __restrict__ locs, const float* __restrict__ logits,
    float* __restrict__ ck2, float* __restrict__ lse_out,
    char* __restrict__ lf) {
    if (blockIdx.x < 32) {
        int gid = blockIdx.x * 256 + threadIdx.x;   // 0..8191
        int T = gid >> 6;
        int l = gid & 63;
        int n = l & 15, q = l >> 4;
        int k = T * 16 + n;

        const float* src = locs + (size_t)k * ZD + q * 8;
        float4 u0 = *(const float4*)(src);
        float4 u1 = *(const float4*)(src + 4);
        float4 u2 = *(const float4*)(src + 32);
        float4 u3 = *(const float4*)(src + 36);
        float a[8] = {u0.x, u0.y, u0.z, u0.w, u1.x, u1.y, u1.z, u1.w};
        float b[8] = {u2.x, u2.y, u2.z, u2.w, u3.x, u3.y, u3.z, u3.w};

        short8 h0, h1, l0, l1;
        float sq = 0.f;
#pragma unroll
        for (int j = 0; j < 8; ++j) {
            unsigned short ha = f2bf(a[j]);
            h0[j] = (short)ha; l0[j] = (short)f2bf(a[j] - bf2f(ha));
            unsigned short hb = f2bf(b[j]);
            h1[j] = (short)hb; l1[j] = (short)f2bf(b[j] - bf2f(hb));
            sq = fmaf(a[j], a[j], sq);
            sq = fmaf(b[j], b[j], sq);
        }
        char* dst = lf + (size_t)T * 4096 + l * 16;
        *(short8*)(dst)        = h0;
        *(short8*)(dst + 1024) = h1;
        *(short8*)(dst + 2048) = l0;
        *(short8*)(dst + 3072) = l1;

        sq += __shfl_xor(sq, 16);
        sq += __shfl_xor(sq, 32);
        if (q == 0) ck2[k] = (logits[k] - sq * (1.0f / 128.0f)) * INV_LN2;
    } else {
        // lse block: 256 threads, wave-shuffle reductions, 2 barriers
        __shared__ float red[4];
        int tid = threadIdx.x;
        int wv = tid >> 6, ln = tid & 63;
        float lm = -INFINITY;
        for (int i = tid; i < K_COMP; i += 256) lm = fmaxf(lm, logits[i]);
#pragma unroll
        for (int d = 1; d < 64; d <<= 1) lm = fmaxf(lm, __shfl_xor(lm, d));
        if (ln == 0) red[wv] = lm;
        __syncthreads();
        float M = fmaxf(fmaxf(red[0], red[1]), fmaxf(red[2], red[3]));
        float ls = 0.f;
        for (int i = tid; i < K_COMP; i += 256) ls += __expf(logits[i] - M);
#pragma unroll
        for (int d = 1; d < 64; d <<= 1) ls += __shfl_xor(ls, d);
        __syncthreads();
        if (ln == 0) red[wv] = ls;
        __syncthreads();
        if (tid == 0) *lse_out = M + __logf(red[0] + red[1] + red[2] + red[3]);
    }
}

// ---------------------------------------------------------------------------
// mix: block = 512 thr = 8 waves = 2 sample-groups(32 samp) x 4 k-groups.
// Per iter: one 16-comp tile, 5 coalesced b128 loads (ring-2), 12 chained
// MFMA, then flat exp2-sum (no online max: w <= ~1.5 provably, no overflow;
// w_max >= ~-60 so fp32 sum keeps all significant terms) + tree argmax.
// ---------------------------------------------------------------------------
__global__ __launch_bounds__(512, 4) void mix_kernel(
    const float* __restrict__ x, const float* __restrict__ locs,
    const char* __restrict__ lf, const float* __restrict__ ck2,
    const float* __restrict__ lse_ptr, float* __restrict__ out) {

    __shared__ float sm[KG][2][32];
    __shared__ float ss[KG][2][32];
    __shared__ int   sa[KG][2][32];
    __shared__ float xsq_sh[64];
    __shared__ int   amax_sh[64];

    const int tid  = threadIdx.x;
    const int lane = tid & 63;
    const int wave = tid >> 6;                                   // 0..7
    const int kg   = __builtin_amdgcn_readfirstlane(wave & 3);   // 0..3
    const int sgp  = __builtin_amdgcn_readfirstlane(wave >> 2);  // 0..1
    const int n    = lane & 15;
    const int quad = lane >> 4;
    const int sA   = blockIdx.x * 64 + sgp * 32 + n;
    const int sB   = sA + 16;

    // ---- B fragments (x) for 2 sample tiles, fp32 -> bf16 hi/lo; xsq partials
    short8 bhA0, bhA1, blA0, blA1, bhB0, bhB1, blB0, blB1;
    {
        const float* xp = x + (size_t)sA * ZD + quad * 8;
        float4 u0 = *(const float4*)(xp);
        float4 u1 = *(const float4*)(xp + 4);
        float4 u2 = *(const float4*)(xp + 32);
        float4 u3 = *(const float4*)(xp + 36);
        const float* yp = x + (size_t)sB * ZD + quad * 8;
        float4 v0 = *(const float4*)(yp);
        float4 v1 = *(const float4*)(yp + 4);
        float4 v2 = *(const float4*)(yp + 32);
        float4 v3 = *(const float4*)(yp + 36);
        float a[8] = {u0.x, u0.y, u0.z, u0.w, u1.x, u1.y, u1.z, u1.w};
        float b[8] = {u2.x, u2.y, u2.z, u2.w, u3.x, u3.y, u3.z, u3.w};
        float c[8] = {v0.x, v0.y, v0.z, v0.w, v1.x, v1.y, v1.z, v1.w};
        float d[8] = {v2.x, v2.y, v2.z, v2.w, v3.x, v3.y, v3.z, v3.w};
        float pa = 0.f, pb = 0.f;
#pragma unroll
        for (int j = 0; j < 8; ++j) {
            unsigned short h;
            h = f2bf(a[j]); bhA0[j] = (short)h; blA0[j] = (short)f2bf(a[j] - bf2f(h));
            h = f2bf(b[j]); bhA1[j] = (short)h; blA1[j] = (short)f2bf(b[j] - bf2f(h));
            h = f2bf(c[j]); bhB0[j] = (short)h; blB0[j] = (short)f2bf(c[j] - bf2f(h));
            h = f2bf(d[j]); bhB1[j] = (short)h; blB1[j] = (short)f2bf(d[j] - bf2f(h));
            pa = fmaf(a[j], a[j], pa); pa = fmaf(b[j], b[j], pa);
            pb = fmaf(c[j], c[j], pb); pb = fmaf(d[j], d[j], pb);
        }
        pa += __shfl_xor(pa, 16); pa += __shfl_xor(pa, 32);
        pb += __shfl_xor(pb, 16); pb += __shfl_xor(pb, 32);
        if (kg == 0) {
            if (quad == 0) xsq_sh[sgp * 32 + n] = pa;
            if (quad == 1) xsq_sh[sgp * 32 + 16 + n] = pb;
        }
    }

    // ---- A-frag stream, ring-2 prefetch, coalesced (lane*16 contiguous)
    const char* aw = lf + (size_t)kg * TILES * 4096 + lane * 16;
    const float* ckw = ck2 + kg * TILES * 16 + quad * 4;
    const int kb0 = kg * TILES * 16 + quad * 4;

    short8 fa[2][4];
    float4 fc[2];

#define LOADA(slot, tt) do {                                     \
    const char* _p = aw + (size_t)(tt) * 4096;                   \
    fa[slot][0] = *(const short8*)(_p);                          \
    fa[slot][1] = *(const short8*)(_p + 1024);                   \
    fa[slot][2] = *(const short8*)(_p + 2048);                   \
    fa[slot][3] = *(const short8*)(_p + 3072);                   \
    fc[slot] = *(const float4*)(ckw + (tt) * 16);                \
} while (0)

    float mA = -1e30f, mB = -1e30f;
    float sA0 = 0.f, sA1 = 0.f, sB0 = 0.f, sB1 = 0.f;
    int aiA = 0, aiB = 0;

#define COMPUTE(slot, tt) do {                                                 \
    v4f accA = {0.f, 0.f, 0.f, 0.f};                                           \
    v4f accB = {0.f, 0.f, 0.f, 0.f};                                           \
    accA = __builtin_amdgcn_mfma_f32_16x16x32_bf16(fa[slot][0], bhA0, accA, 0, 0, 0); \
    accB = __builtin_amdgcn_mfma_f32_16x16x32_bf16(fa[slot][0], bhB0, accB, 0, 0, 0); \
    accA = __builtin_amdgcn_mfma_f32_16x16x32_bf16(fa[slot][1], bhA1, accA, 0, 0, 0); \
    accB = __builtin_amdgcn_mfma_f32_16x16x32_bf16(fa[slot][1], bhB1, accB, 0, 0, 0); \
    accA = __builtin_amdgcn_mfma_f32_16x16x32_bf16(fa[slot][0], blA0, accA, 0, 0, 0); \
    accB = __builtin_amdgcn_mfma_f32_16x16x32_bf16(fa[slot][0], blB0, accB, 0, 0, 0); \
    accA = __builtin_amdgcn_mfma_f32_16x16x32_bf16(fa[slot][1], blA1, accA, 0, 0, 0); \
    accB = __builtin_amdgcn_mfma_f32_16x16x32_bf16(fa[slot][1], blB1, accB, 0, 0, 0); \
    accA = __builtin_amdgcn_mfma_f32_16x16x32_bf16(fa[slot][2], bhA0, accA, 0, 0, 0); \
    accB = __builtin_amdgcn_mfma_f32_16x16x32_bf16(fa[slot][2], bhB0, accB, 0, 0, 0); \
    accA = __builtin_amdgcn_mfma_f32_16x16x32_bf16(fa[slot][3], bhA1, accA, 0, 0, 0); \
    accB = __builtin_amdgcn_mfma_f32_16x16x32_bf16(fa[slot][3], bhB1, accB, 0, 0, 0); \
    const int kb = kb0 + (tt) * 16;                                            \
    float4 cc = fc[slot];                                                      \
    {                                                                          \
        float w0 = fmaf(accA.x, S2C, cc.x);                                    \
        float w1 = fmaf(accA.y, S2C, cc.y);                                    \
        float w2 = fmaf(accA.z, S2C, cc.z);                                    \
        float w3 = fmaf(accA.w, S2C, cc.w);                                    \
        sA0 += EXP2(w0) + EXP2(w1);                                            \
        sA1 += EXP2(w2) + EXP2(w3);                                            \
        float t01 = fmaxf(w0, w1); int i01 = (w1 > w0) ? (kb + 1) : (kb + 0);  \
        float t23 = fmaxf(w2, w3); int i23 = (w3 > w2) ? (kb + 3) : (kb + 2);  \
        float tt2 = fmaxf(t01, t23); int it = (t23 > t01) ? i23 : i01;         \
        aiA = (tt2 > mA) ? it : aiA; mA = fmaxf(mA, tt2);                      \
    }                                                                          \
    {                                                                          \
        float w0 = fmaf(accB.x, S2C, cc.x);                                    \
        float w1 = fmaf(accB.y, S2C, cc.y);                                    \
        float w2 = fmaf(accB.z, S2C, cc.z);                                    \
        float w3 = fmaf(accB.w, S2C, cc.w);                                    \
        sB0 += EXP2(w0) + EXP2(w1);                                            \
        sB1 += EXP2(w2) + EXP2(w3);                                            \
        float t01 = fmaxf(w0, w1); int i01 = (w1 > w0) ? (kb + 1) : (kb + 0);  \
        float t23 = fmaxf(w2, w3); int i23 = (w3 > w2) ? (kb + 3) : (kb + 2);  \
        float tt2 = fmaxf(t01, t23); int it = (t23 > t01) ? i23 : i01;         \
        aiB = (tt2 > mB) ? it : aiB; mB = fmaxf(mB, tt2);                      \
    }                                                                          \
} while (0)

    LOADA(0, 0);
    for (int t = 0; t < TILES; t += 2) {
        int t1 = (t + 1 < TILES) ? (t + 1) : (TILES - 1);
        LOADA(1, t1);
        COMPUTE(0, t);
        int t2 = (t + 2 < TILES) ? (t + 2) : (TILES - 1);
        LOADA(0, t2);
        COMPUTE(1, t + 1);
    }

    float sumA = sA0 + sA1;
    float sumB = sB0 + sB1;

    // ---- merge the 4 quads (disjoint comp subsets, same sample column)
#pragma unroll
    for (int d = 16; d <= 32; d <<= 1) {
        sumA += __shfl_xor(sumA, d);
        sumB += __shfl_xor(sumB, d);
        float om; int oa;
        om = __shfl_xor(mA, d); oa = __shfl_xor(aiA, d);
        aiA = (om > mA || (om == mA && oa < aiA)) ? oa : aiA;
        mA = fmaxf(mA, om);
        om = __shfl_xor(mB, d); oa = __shfl_xor(aiB, d);
        aiB = (om > mB || (om == mB && oa < aiB)) ? oa : aiB;
        mB = fmaxf(mB, om);
    }
    if (quad == 0) { sm[kg][sgp][n] = mA; ss[kg][sgp][n] = sumA; sa[kg][sgp][n] = aiA; }
    if (quad == 1) { sm[kg][sgp][16 + n] = mB; ss[kg][sgp][16 + n] = sumB; sa[kg][sgp][16 + n] = aiB; }
    __syncthreads();

    // ---- merge KG k-groups, write log_prob, stash argmax
    if (tid < 64) {
        int g = tid >> 5, sl = tid & 31;
        float M = -1e30f, S = 0.f; int A = 0;
#pragma unroll
        for (int k = 0; k < KG; ++k) {
            float mw = sm[k][g][sl];
            int aw2 = sa[k][g][sl];
            S += ss[k][g][sl];
            A = (mw > M || (mw == M && aw2 < A)) ? aw2 : A;  // ascending kg order
            M = fmaxf(M, mw);
        }
        float bias = -xsq_sh[tid] * (1.0f / 128.0f) - LNC;
        out[blockIdx.x * 64 + tid] = fmaf(__log2f(S), LN2F, bias - lse_ptr[0]);
        amax_sh[tid] = A;
    }
    __syncthreads();

    // ---- quantized = locs[argmax], cooperative coalesced float4 writes
    const float4* lq = (const float4*)locs;
    float4* oq = (float4*)(out + N_SAMP + (size_t)blockIdx.x * 64 * ZD);
#pragma unroll
    for (int i = tid; i < 64 * (ZD / 4); i += 512) {
        int r = i >> 4, c = i & 15;
        oq[i] = lq[(size_t)amax_sh[r] * (ZD / 4) + c];
    }
#undef LOADA
#undef COMPUTE
}

extern "C" void kernel_launch(void* const* d_in, const int* in_sizes, int n_in,
                              void* d_out, int out_size, void* d_ws, size_t ws_size,
                              hipStream_t stream) {
    const float* x      = (const float*)d_in[0];
    const float* locs   = (const float*)d_in[1];
    const float* logits = (const float*)d_in[2];
    float* out = (float*)d_out;

    float* ck2 = (float*)d_ws;                 // 2048 floats
    float* lse = ck2 + K_COMP;                 // 1 float
    char*  lf  = (char*)d_ws + 16384;          // 512 KB fragment-linearized locs

    prep_kernel<<<33, 256, 0, stream>>>(locs, logits, ck2, lse, lf);
    mix_kernel<<<N_SAMP / 64, 512, 0, stream>>>(x, locs, lf, ck2, lse, out);
}

// Round 5
// 95.510 us; speedup vs baseline: 10.6285x; 1.0171x over previous
//
#include <hip/hip_runtime.h>
#include <math.h>

#define N_SAMP 32768
#define K_COMP 2048
#define ZD 64
#define LNC 191.896324792608546f   // 64*(0.5*log(2pi) + 0.5*log(64))
#define LN2F 0.69314718055994531f
#define INV_LN2 1.44269504088896340f
// w = dot*(1/(64 ln2)) + ck2 ; wlp_nat = w*ln2 + bias_nat
#define S2C 0.02254211001388974f   // 1/(64*ln2)

#define KG 4                       // k-groups = waves per block
#define TILES (K_COMP / 16 / KG)   // 32 tiles per wave

typedef __attribute__((ext_vector_type(8))) short short8;
typedef __attribute__((ext_vector_type(4))) float v4f;

#if __has_builtin(__builtin_amdgcn_exp2f)
#define EXP2(x) __builtin_amdgcn_exp2f(x)
#else
#define EXP2(x) exp2f(x)
#endif

__device__ inline unsigned short f2bf(float f) {
    unsigned int u = __float_as_uint(f);
    u += 0x7fffu + ((u >> 16) & 1u);  // RNE
    return (unsigned short)(u >> 16);
}
__device__ inline float bf2f(unsigned short h) {
    return __uint_as_float(((unsigned int)h) << 16);
}

// ---------------------------------------------------------------------------
// prep: blocks 0..31 build fragment-linearized locs hi/lo (lf) + ck2.
//       block 32 computes lse = logsumexp(logits) concurrently.
// lf layout: tile T (16 comps) -> 4 KB: 4 regions {hiA d0-31, hiA d32-63,
// loA d0-31, loA d32-63} x 64 lanes x 16 B == mix's A-fragment order.
// ---------------------------------------------------------------------------
__global__ __launch_bounds__(256) void prep_kernel(
    const float* __restrict__ locs, const float* __restrict__ logits,
    float* __restrict__ ck2, float* __restrict__ lse_out,
    char* __restrict__ lf) {
    if (blockIdx.x < 32) {
        int gid = blockIdx.x * 256 + threadIdx.x;   // 0..8191
        int T = gid >> 6;
        int l = gid & 63;
        int n = l & 15, q = l >> 4;
        int k = T * 16 + n;

        const float* src = locs + (size_t)k * ZD + q * 8;
        float4 u0 = *(const float4*)(src);
        float4 u1 = *(const float4*)(src + 4);
        float4 u2 = *(const float4*)(src + 32);
        float4 u3 = *(const float4*)(src + 36);
        float a[8] = {u0.x, u0.y, u0.z, u0.w, u1.x, u1.y, u1.z, u1.w};
        float b[8] = {u2.x, u2.y, u2.z, u2.w, u3.x, u3.y, u3.z, u3.w};

        short8 h0, h1, l0, l1;
        float sq = 0.f;
#pragma unroll
        for (int j = 0; j < 8; ++j) {
            unsigned short ha = f2bf(a[j]);
            h0[j] = (short)ha; l0[j] = (short)f2bf(a[j] - bf2f(ha));
            unsigned short hb = f2bf(b[j]);
            h1[j] = (short)hb; l1[j] = (short)f2bf(b[j] - bf2f(hb));
            sq = fmaf(a[j], a[j], sq);
            sq = fmaf(b[j], b[j], sq);
        }
        char* dst = lf + (size_t)T * 4096 + l * 16;
        *(short8*)(dst)        = h0;
        *(short8*)(dst + 1024) = h1;
        *(short8*)(dst + 2048) = l0;
        *(short8*)(dst + 3072) = l1;

        sq += __shfl_xor(sq, 16);
        sq += __shfl_xor(sq, 32);
        if (q == 0) ck2[k] = (logits[k] - sq * (1.0f / 128.0f)) * INV_LN2;
    } else {
        __shared__ float red[4];
        int tid = threadIdx.x;
        int wv = tid >> 6, ln = tid & 63;
        float lm = -INFINITY;
        for (int i = tid; i < K_COMP; i += 256) lm = fmaxf(lm, logits[i]);
#pragma unroll
        for (int d = 1; d < 64; d <<= 1) lm = fmaxf(lm, __shfl_xor(lm, d));
        if (ln == 0) red[wv] = lm;
        __syncthreads();
        float M = fmaxf(fmaxf(red[0], red[1]), fmaxf(red[2], red[3]));
        float ls = 0.f;
        for (int i = tid; i < K_COMP; i += 256) ls += __expf(logits[i] - M);
#pragma unroll
        for (int d = 1; d < 64; d <<= 1) ls += __shfl_xor(ls, d);
        __syncthreads();
        if (ln == 0) red[wv] = ls;
        __syncthreads();
        if (tid == 0) *lse_out = M + __logf(red[0] + red[1] + red[2] + red[3]);
    }
}

// ---------------------------------------------------------------------------
// mix: block = 256 thr = 4 waves = 4 k-groups; EVERY wave holds B-frags for
// all 64 samples of the block (4 tiles) in registers. Per iter: one 16-comp
// tile = 4 coalesced b128 A-loads (ring-2 prefetch) + 24 MFMA (4 indep
// chains) + flat exp2-sum (w <= ~1.5 provably; no online max) + tree argmax.
// ---------------------------------------------------------------------------
__global__ __launch_bounds__(256, 2) void mix_kernel(
    const float* __restrict__ x, const float* __restrict__ locs,
    const char* __restrict__ lf, const float* __restrict__ ck2,
    const float* __restrict__ lse_ptr, float* __restrict__ out) {

    __shared__ float sm[KG][64];
    __shared__ float ss[KG][64];
    __shared__ int   sa[KG][64];
    __shared__ int   amax_sh[64];

    const int tid  = threadIdx.x;
    const int lane = tid & 63;
    const int kg   = __builtin_amdgcn_readfirstlane(tid >> 6);  // 0..3
    const int n    = lane & 15;
    const int quad = lane >> 4;
    const int sbase = blockIdx.x * 64;

    // ---- B fragments (x) for 4 sample tiles (64 samples), hi/lo split
    short8 bh[4][2], bl[4][2];
    float xs[4];
#pragma unroll
    for (int bt = 0; bt < 4; ++bt) {
        const float* xp = x + (size_t)(sbase + bt * 16 + n) * ZD + quad * 8;
        float4 u0 = *(const float4*)(xp);
        float4 u1 = *(const float4*)(xp + 4);
        float4 u2 = *(const float4*)(xp + 32);
        float4 u3 = *(const float4*)(xp + 36);
        float a[8] = {u0.x, u0.y, u0.z, u0.w, u1.x, u1.y, u1.z, u1.w};
        float b[8] = {u2.x, u2.y, u2.z, u2.w, u3.x, u3.y, u3.z, u3.w};
        float p = 0.f;
#pragma unroll
        for (int j = 0; j < 8; ++j) {
            unsigned short h;
            h = f2bf(a[j]); bh[bt][0][j] = (short)h; bl[bt][0][j] = (short)f2bf(a[j] - bf2f(h));
            h = f2bf(b[j]); bh[bt][1][j] = (short)h; bl[bt][1][j] = (short)f2bf(b[j] - bf2f(h));
            p = fmaf(a[j], a[j], p);
            p = fmaf(b[j], b[j], p);
        }
        p += __shfl_xor(p, 16);
        p += __shfl_xor(p, 32);
        xs[bt] = p;   // ||x||^2 of sample bt*16+n (all quads hold it)
    }

    // ---- A-frag stream, ring-2 prefetch, coalesced (lane*16 contiguous)
    const char* aw = lf + (size_t)kg * TILES * 4096 + lane * 16;
    const float* ckw = ck2 + kg * TILES * 16 + quad * 4;
    const int kb0 = kg * TILES * 16 + quad * 4;

    short8 fa[2][4];
    float4 fc[2];

#define LOADA(slot, tt) do {                                     \
    const char* _p = aw + (size_t)(tt) * 4096;                   \
    fa[slot][0] = *(const short8*)(_p);                          \
    fa[slot][1] = *(const short8*)(_p + 1024);                   \
    fa[slot][2] = *(const short8*)(_p + 2048);                   \
    fa[slot][3] = *(const short8*)(_p + 3072);                   \
    fc[slot] = *(const float4*)(ckw + (tt) * 16);                \
} while (0)

    float mm[4] = {-1e30f, -1e30f, -1e30f, -1e30f};
    float s0[4] = {0.f, 0.f, 0.f, 0.f};
    float s1[4] = {0.f, 0.f, 0.f, 0.f};
    int   ai[4] = {0, 0, 0, 0};

#define COMPUTE(slot, tt) do {                                                  \
    v4f acc[4];                                                                 \
    _Pragma("unroll")                                                           \
    for (int bt = 0; bt < 4; ++bt) acc[bt] = (v4f){0.f, 0.f, 0.f, 0.f};         \
    _Pragma("unroll")                                                           \
    for (int h = 0; h < 2; ++h) {                                               \
        _Pragma("unroll")                                                       \
        for (int bt = 0; bt < 4; ++bt)                                          \
            acc[bt] = __builtin_amdgcn_mfma_f32_16x16x32_bf16(                  \
                fa[slot][h], bh[bt][h], acc[bt], 0, 0, 0);                      \
    }                                                                           \
    _Pragma("unroll")                                                           \
    for (int h = 0; h < 2; ++h) {                                               \
        _Pragma("unroll")                                                       \
        for (int bt = 0; bt < 4; ++bt)                                          \
            acc[bt] = __builtin_amdgcn_mfma_f32_16x16x32_bf16(                  \
                fa[slot][h], bl[bt][h], acc[bt], 0, 0, 0);                      \
    }                                                                           \
    _Pragma("unroll")                                                           \
    for (int h = 0; h < 2; ++h) {                                               \
        _Pragma("unroll")                                                       \
        for (int bt = 0; bt < 4; ++bt)                                          \
            acc[bt] = __builtin_amdgcn_mfma_f32_16x16x32_bf16(                  \
                fa[slot][2 + h], bh[bt][h], acc[bt], 0, 0, 0);                  \
    }                                                                           \
    const int kb = kb0 + (tt) * 16;                                             \
    float4 cc = fc[slot];                                                       \
    _Pragma("unroll")                                                           \
    for (int bt = 0; bt < 4; ++bt) {                                            \
        float w0 = fmaf(acc[bt].x, S2C, cc.x);                                  \
        float w1 = fmaf(acc[bt].y, S2C, cc.y);                                  \
        float w2 = fmaf(acc[bt].z, S2C, cc.z);                                  \
        float w3 = fmaf(acc[bt].w, S2C, cc.w);                                  \
        s0[bt] += EXP2(w0) + EXP2(w1);                                          \
        s1[bt] += EXP2(w2) + EXP2(w3);                                          \
        float t01 = fmaxf(w0, w1); int i01 = (w1 > w0) ? (kb + 1) : (kb + 0);   \
        float t23 = fmaxf(w2, w3); int i23 = (w3 > w2) ? (kb + 3) : (kb + 2);   \
        float tt2 = fmaxf(t01, t23); int it = (t23 > t01) ? i23 : i01;          \
        ai[bt] = (tt2 > mm[bt]) ? it : ai[bt];                                  \
        mm[bt] = fmaxf(mm[bt], tt2);                                            \
    }                                                                           \
} while (0)

    LOADA(0, 0);
    for (int t = 0; t < TILES; t += 2) {
        int t1 = (t + 1 < TILES) ? (t + 1) : (TILES - 1);
        LOADA(1, t1);
        COMPUTE(0, t);
        int t2 = (t + 2 < TILES) ? (t + 2) : (TILES - 1);
        LOADA(0, t2);
        COMPUTE(1, t + 1);
    }

    // ---- merge the 4 quads (disjoint comp subsets, same sample column)
#pragma unroll
    for (int bt = 0; bt < 4; ++bt) {
        float sum = s0[bt] + s1[bt];
#pragma unroll
        for (int d = 16; d <= 32; d <<= 1) {
            sum += __shfl_xor(sum, d);
            float om = __shfl_xor(mm[bt], d);
            int   oa = __shfl_xor(ai[bt], d);
            ai[bt] = (om > mm[bt] || (om == mm[bt] && oa < ai[bt])) ? oa : ai[bt];
            mm[bt] = fmaxf(mm[bt], om);
        }
        if (quad == 0) {
            sm[kg][bt * 16 + n] = mm[bt];
            ss[kg][bt * 16 + n] = sum;
            sa[kg][bt * 16 + n] = ai[bt];
        }
    }
    __syncthreads();

    // ---- merge KG k-groups (wave 0), write log_prob, stash argmax
    if (tid < 64) {
        float M = -1e30f, S = 0.f;
        int A = 0;
#pragma unroll
        for (int k = 0; k < KG; ++k) {
            float mw = sm[k][tid];
            int aw2 = sa[k][tid];
            S += ss[k][tid];
            A = (mw > M || (mw == M && aw2 < A)) ? aw2 : A;  // ascending kg
            M = fmaxf(M, mw);
        }
        // wave 0 holds xs[] in regs; lane tid needs xs[tid>>4] == xs[quad]
        float myxs = (quad == 0) ? xs[0] : (quad == 1) ? xs[1]
                   : (quad == 2) ? xs[2] : xs[3];
        float bias = -myxs * (1.0f / 128.0f) - LNC;
        out[sbase + tid] = fmaf(__log2f(S), LN2F, bias - lse_ptr[0]);
        amax_sh[tid] = A;
    }
    __syncthreads();

    // ---- quantized = locs[argmax], cooperative coalesced float4 writes
    const float4* lq = (const float4*)locs;
    float4* oq = (float4*)(out + N_SAMP + (size_t)sbase * ZD);
#pragma unroll
    for (int i = tid; i < 64 * (ZD / 4); i += 256) {
        int r = i >> 4, c = i & 15;
        oq[i] = lq[(size_t)amax_sh[r] * (ZD / 4) + c];
    }
#undef LOADA
#undef COMPUTE
}

extern "C" void kernel_launch(void* const* d_in, const int* in_sizes, int n_in,
                              void* d_out, int out_size, void* d_ws, size_t ws_size,
                              hipStream_t stream) {
    const float* x      = (const float*)d_in[0];
    const float* locs   = (const float*)d_in[1];
    const float* logits = (const float*)d_in[2];
    float* out = (float*)d_out;

    float* ck2 = (float*)d_ws;                 // 2048 floats
    float* lse = ck2 + K_COMP;                 // 1 float
    char*  lf  = (char*)d_ws + 16384;          // 512 KB fragment-linearized locs

    prep_kernel<<<33, 256, 0, stream>>>(locs, logits, ck2, lse, lf);
    mix_kernel<<<N_SAMP / 64, 256, 0, stream>>>(x, locs, lf, ck2, lse, out);
}